// Round 5
// baseline (204.488 us; speedup 1.0000x reference)
//
#include <hip/hip_runtime.h>
#include <stdint.h>

// MeshConvPoint: B=8, C=64, V=25000, D=12, O=64
// out[b,o,v] = bias[o] + sum_c W0[o,c]*x[b,c,v] + (1/deg)*sum_{d<deg} y1[b,o,nbr[b,v,d]]
//
// R5: gather restructured to 8 lanes/vertex (slot = lane>>3, chunk j = lane&7).
// One gather instruction now covers 8 whole contiguous 128B y1 rows (~16 segs)
// instead of 64 divergent 16B requests (R4: TA-bound, 64us @ 20% HBM, 15% VALU).
// ygemm_mfma unchanged from R4 (isolate the experiment; it'll show in top-5).
// XCD pin: blockIdx.x & 7 == batch in producer and consumer; per-batch y1
// (3.2 MB bf16) lives in that XCD's 4 MB L2.

#define NB 8
#define NC 64
#define NV 25000
#define ND 12
#define NO 64
#define GT 391         // ceil(25000/64)  vertex tiles for gemm (64 v / block)
#define GVT 782        // ceil(25000/32)  vertex tiles for gather (32 v / block)

typedef uint32_t u32x4 __attribute__((ext_vector_type(4)));
typedef uint32_t u32x2 __attribute__((ext_vector_type(2)));
typedef __bf16  bf16x8 __attribute__((ext_vector_type(8)));
typedef float   f32x4  __attribute__((ext_vector_type(4)));

__device__ inline uint32_t bf16pack(float a, float b) {
    uint32_t ua = __float_as_uint(a), ub = __float_as_uint(b);
    ua = (ua + 0x7fffu + ((ua >> 16) & 1u)) >> 16;
    ub = (ub + 0x7fffu + ((ub >> 16) & 1u)) >> 16;
    return ua | (ub << 16);
}
__device__ inline float blo(uint32_t u) { return __uint_as_float(u << 16); }
__device__ inline float bhi(uint32_t u) { return __uint_as_float(u & 0xffff0000u); }

// ---- K0: W[o][c][k] -> Wcb[m][c] bf16, m = k*64 + o  (A-operand friendly, k-major rows)
__global__ __launch_bounds__(256) void wt_kernel(const float* __restrict__ W,
                                                 uint32_t* __restrict__ Wcb) {
    int i = blockIdx.x * 256 + threadIdx.x;  // i in [0, 4096)
    int m = i >> 5;             // 0..127
    int c = (i & 31) * 2;       // 0..62 even
    int k = m >> 6;             // plane
    int o = m & 63;
    float s0 = W[o * (NC * 2) + c * 2 + k];
    float s1 = W[o * (NC * 2) + (c + 1) * 2 + k];
    Wcb[i] = bf16pack(s0, s1);
}

// ---- K1: MFMA GEMM, both planes at once (unchanged from R4) ----
__global__ __launch_bounds__(256) void ygemm_mfma(const float* __restrict__ x,
                                                  const uint32_t* __restrict__ Wcb,
                                                  const float* __restrict__ bias,
                                                  uint32_t* __restrict__ y0,
                                                  uint32_t* __restrict__ y1) {
    const int b = blockIdx.x & 7;      // XCD pin
    const int tile = blockIdx.x >> 3;
    const int wave = threadIdx.x >> 6;
    const int lane = threadIdx.x & 63;
    const int l15 = lane & 15;
    const int lq = lane >> 4;          // quad 0..3
    const int v = tile * 64 + wave * 16 + l15;
    const int vc = v < NV ? v : NV - 1;
    const float* xb = x + (size_t)b * NC * NV;

    // B fragments: B[k][n], n = lane&15, k = lq*8 + j
    union BU { uint32_t u[4]; bf16x8 v; } bu[2];
#pragma unroll
    for (int kt = 0; kt < 2; ++kt) {
        const float* xc = xb + (size_t)(kt * 32 + lq * 8) * NV + vc;
#pragma unroll
        for (int jp = 0; jp < 4; ++jp) {
            float s0 = __builtin_nontemporal_load(xc + (size_t)(2 * jp) * NV);
            float s1 = __builtin_nontemporal_load(xc + (size_t)(2 * jp + 1) * NV);
            bu[kt].u[jp] = bf16pack(s0, s1);
        }
    }

    f32x4 acc[8];
#pragma unroll
    for (int mt = 0; mt < 8; ++mt) acc[mt] = (f32x4){0.f, 0.f, 0.f, 0.f};

#pragma unroll
    for (int mt = 0; mt < 8; ++mt) {
#pragma unroll
        for (int kt = 0; kt < 2; ++kt) {
            union { u32x4 q; bf16x8 v; } au;
            au.q = *(const u32x4*)(Wcb + (size_t)(mt * 16 + l15) * 32 + kt * 16 + lq * 4);
            acc[mt] = __builtin_amdgcn_mfma_f32_16x16x32_bf16(au.v, bu[kt].v, acc[mt], 0, 0, 0);
        }
    }

    // D: lane holds D[m = mt*16 + lq*4 + r][n = v]
    if (v < NV) {
        uint32_t* yr0 = y0 + ((size_t)b * NV + v) * 32;
        uint32_t* yr1 = y1 + ((size_t)b * NV + v) * 32;
#pragma unroll
        for (int mt = 0; mt < 8; ++mt) {
            const int mo = mt * 16 + lq * 4;
            f32x4 a = acc[mt];
            if (mt < 4) {  // plane 0: + bias, nt store (read exactly once later)
                const float* bp = bias + mo;
                a[0] += bp[0]; a[1] += bp[1]; a[2] += bp[2]; a[3] += bp[3];
                u32x2 p = {bf16pack(a[0], a[1]), bf16pack(a[2], a[3])};
                __builtin_nontemporal_store(p, (u32x2*)(yr0 + (mo >> 1)));
            } else {       // plane 1: hot gather target, keep cached in L2
                u32x2 p = {bf16pack(a[0], a[1]), bf16pack(a[2], a[3])};
                *(u32x2*)(yr1 + ((mo - 64) >> 1)) = p;
            }
        }
    }
}

// ---- K2: gather, 8 lanes per vertex ----
// slot s = lane>>3 owns vertex v = tile*32 + wave*8 + s; lane j = lane&7 owns
// the 16B chunk j of every 128B y1 row (o = j*8 .. j*8+7).
__global__ __launch_bounds__(256) void gather_out(const int* __restrict__ nbr,
                                                  const int* __restrict__ deg,
                                                  const uint32_t* __restrict__ y0,
                                                  const uint32_t* __restrict__ y1,
                                                  float* __restrict__ out) {
    const int b = blockIdx.x & 7;  // same XCD pin as producer
    const int tile = blockIdx.x >> 3;
    const int lane = threadIdx.x & 63;
    const int wave = threadIdx.x >> 6;
    const int s = lane >> 3;
    const int j = lane & 7;
    const int v = tile * 32 + wave * 8 + s;
    const int vc = v < NV ? v : NV - 1;
    const bool valid = (v < NV);
    const size_t bv = (size_t)b * NV + vc;

    // all 12 neighbor indices (48B, int4-aligned since 48 % 16 == 0)
    int idxr[ND];
    {
        const int4* p = reinterpret_cast<const int4*>(nbr + bv * ND);
        int4 a0 = p[0], a1 = p[1], a2 = p[2];
        idxr[0] = a0.x; idxr[1] = a0.y; idxr[2]  = a0.z; idxr[3]  = a0.w;
        idxr[4] = a1.x; idxr[5] = a1.y; idxr[6]  = a1.z; idxr[7]  = a1.w;
        idxr[8] = a2.x; idxr[9] = a2.y; idxr[10] = a2.z; idxr[11] = a2.w;
    }
    const int dg = deg[bv];
    const float inv = 1.0f / (float)dg;
    const uint32_t* y1b = y1 + (size_t)b * NV * 32;

    // self row chunk (read once, nt)
    u32x4 su = __builtin_nontemporal_load(
        reinterpret_cast<const u32x4*>(y0 + bv * 32) + j);

    // phase 1: issue all masked row-chunk loads (MLP: up to 12 outstanding)
    u32x4 rows[ND];
#pragma unroll
    for (int d = 0; d < ND; ++d) {
        if (d < dg)
            rows[d] = *(reinterpret_cast<const u32x4*>(y1b + (size_t)idxr[d] * 32) + j);
    }

    // phase 2: accumulate
    float ns[8];
#pragma unroll
    for (int t = 0; t < 8; ++t) ns[t] = 0.0f;
#pragma unroll
    for (int d = 0; d < ND; ++d) {
        if (d < dg) {
            u32x4 u = rows[d];
            ns[0] += blo(u[0]); ns[1] += bhi(u[0]);
            ns[2] += blo(u[1]); ns[3] += bhi(u[1]);
            ns[4] += blo(u[2]); ns[5] += bhi(u[2]);
            ns[6] += blo(u[3]); ns[7] += bhi(u[3]);
        }
    }

    if (valid) {
        float r[8];
        r[0] = blo(su[0]); r[1] = bhi(su[0]); r[2] = blo(su[1]); r[3] = bhi(su[1]);
        r[4] = blo(su[2]); r[5] = bhi(su[2]); r[6] = blo(su[3]); r[7] = bhi(su[3]);
#pragma unroll
        for (int t = 0; t < 8; ++t) {
            float val = __builtin_fmaf(inv, ns[t], r[t]);
            __builtin_nontemporal_store(
                val, out + ((size_t)b * NO + j * 8 + t) * NV + v);
        }
    }
}

// ---- Fallback (workspace too small): correct but slow ----
__global__ __launch_bounds__(64) void fallback_kernel(const float* __restrict__ x,
                                                      const int* __restrict__ nbr,
                                                      const int* __restrict__ deg,
                                                      const float* __restrict__ W,
                                                      const float* __restrict__ bias,
                                                      float* __restrict__ out) {
    const int bvi = blockIdx.x;
    const int b = bvi / NV, v = bvi % NV;
    const int o = threadIdx.x;
    const int degv = deg[bvi];
    const float inv = 1.0f / (float)degv;
    float acc = bias[o];
    for (int c = 0; c < NC; ++c) {
        const float* xc = x + ((size_t)b * NC + c) * NV;
        float m = 0.0f;
        for (int d = 0; d < degv; ++d) m += xc[nbr[(size_t)bvi * ND + d]];
        acc += W[o * (NC * 2) + c * 2] * xc[v] + W[o * (NC * 2) + c * 2 + 1] * (m * inv);
    }
    out[((size_t)b * NO + o) * NV + v] = acc;
}

extern "C" void kernel_launch(void* const* d_in, const int* in_sizes, int n_in,
                              void* d_out, int out_size, void* d_ws, size_t ws_size,
                              hipStream_t stream) {
    const float* x    = (const float*)d_in[0];
    const int*   nbr  = (const int*)d_in[1];
    const int*   deg  = (const int*)d_in[2];
    const float* W    = (const float*)d_in[3];
    const float* bias = (const float*)d_in[4];
    float* out = (float*)d_out;

    const size_t wcb_dw = 4096;                   // 128x64 bf16 as dwords
    const size_t yplane = (size_t)NB * NV * 32;   // dwords per plane
    const size_t need = (wcb_dw + 2 * yplane) * 4;
    if (ws_size >= need) {
        uint32_t* Wcb = (uint32_t*)d_ws;
        uint32_t* y0 = Wcb + wcb_dw;
        uint32_t* y1 = y0 + yplane;
        wt_kernel<<<dim3(16), 256, 0, stream>>>(W, Wcb);
        ygemm_mfma<<<dim3(NB * GT), 256, 0, stream>>>(x, Wcb, bias, y0, y1);
        gather_out<<<dim3(NB * GVT), 256, 0, stream>>>(nbr, deg, y0, y1, out);
    } else {
        fallback_kernel<<<dim3(NB * NV), 64, 0, stream>>>(x, nbr, deg, W, bias, out);
    }
}

// Round 6
// 177.225 us; speedup vs baseline: 1.1538x; 1.1538x over previous
//
#include <hip/hip_runtime.h>
#include <stdint.h>

// MeshConvPoint: B=8, C=64, V=25000, D=12, O=64
// out[b,o,v] = bias[o] + sum_c W0[o,c]*x[b,c,v] + (1/deg)*sum_{d<deg} y1[b,o,nbr[b,v,d]]
//
// R6: R5's 8-lane/vertex gather (coalesced 128B row loads) + LDS transpose so
// stores are 2 o-rows x 32 consecutive v per instruction (full 64B lines).
// R5 lesson: 8-v-per-wave direct stores made 32B segments -> WRITE 54->89 MB,
// nullifying the gather win. ygemm_mfma unchanged (isolation).
// XCD pin: blockIdx.x & 7 == batch in producer and consumer; per-batch y1
// (3.2 MB bf16) lives in that XCD's 4 MB L2.

#define NB 8
#define NC 64
#define NV 25000
#define ND 12
#define NO 64
#define GT 391         // ceil(25000/64)  vertex tiles for gemm (64 v / block)
#define GVT 782        // ceil(25000/32)  vertex tiles for gather (32 v / block)

typedef uint32_t u32x4 __attribute__((ext_vector_type(4)));
typedef uint32_t u32x2 __attribute__((ext_vector_type(2)));
typedef __bf16  bf16x8 __attribute__((ext_vector_type(8)));
typedef float   f32x4  __attribute__((ext_vector_type(4)));

__device__ inline uint32_t bf16pack(float a, float b) {
    uint32_t ua = __float_as_uint(a), ub = __float_as_uint(b);
    ua = (ua + 0x7fffu + ((ua >> 16) & 1u)) >> 16;
    ub = (ub + 0x7fffu + ((ub >> 16) & 1u)) >> 16;
    return ua | (ub << 16);
}
__device__ inline float blo(uint32_t u) { return __uint_as_float(u << 16); }
__device__ inline float bhi(uint32_t u) { return __uint_as_float(u & 0xffff0000u); }

// ---- K0: W[o][c][k] -> Wcb[m][c] bf16, m = k*64 + o ----
__global__ __launch_bounds__(256) void wt_kernel(const float* __restrict__ W,
                                                 uint32_t* __restrict__ Wcb) {
    int i = blockIdx.x * 256 + threadIdx.x;  // i in [0, 4096)
    int m = i >> 5;             // 0..127
    int c = (i & 31) * 2;       // 0..62 even
    int k = m >> 6;             // plane
    int o = m & 63;
    float s0 = W[o * (NC * 2) + c * 2 + k];
    float s1 = W[o * (NC * 2) + (c + 1) * 2 + k];
    Wcb[i] = bf16pack(s0, s1);
}

// ---- K1: MFMA GEMM, both planes at once (unchanged from R4/R5) ----
__global__ __launch_bounds__(256) void ygemm_mfma(const float* __restrict__ x,
                                                  const uint32_t* __restrict__ Wcb,
                                                  const float* __restrict__ bias,
                                                  uint32_t* __restrict__ y0,
                                                  uint32_t* __restrict__ y1) {
    const int b = blockIdx.x & 7;      // XCD pin
    const int tile = blockIdx.x >> 3;
    const int wave = threadIdx.x >> 6;
    const int lane = threadIdx.x & 63;
    const int l15 = lane & 15;
    const int lq = lane >> 4;          // quad 0..3
    const int v = tile * 64 + wave * 16 + l15;
    const int vc = v < NV ? v : NV - 1;
    const float* xb = x + (size_t)b * NC * NV;

    union BU { uint32_t u[4]; bf16x8 v; } bu[2];
#pragma unroll
    for (int kt = 0; kt < 2; ++kt) {
        const float* xc = xb + (size_t)(kt * 32 + lq * 8) * NV + vc;
#pragma unroll
        for (int jp = 0; jp < 4; ++jp) {
            float s0 = __builtin_nontemporal_load(xc + (size_t)(2 * jp) * NV);
            float s1 = __builtin_nontemporal_load(xc + (size_t)(2 * jp + 1) * NV);
            bu[kt].u[jp] = bf16pack(s0, s1);
        }
    }

    f32x4 acc[8];
#pragma unroll
    for (int mt = 0; mt < 8; ++mt) acc[mt] = (f32x4){0.f, 0.f, 0.f, 0.f};

#pragma unroll
    for (int mt = 0; mt < 8; ++mt) {
#pragma unroll
        for (int kt = 0; kt < 2; ++kt) {
            union { u32x4 q; bf16x8 v; } au;
            au.q = *(const u32x4*)(Wcb + (size_t)(mt * 16 + l15) * 32 + kt * 16 + lq * 4);
            acc[mt] = __builtin_amdgcn_mfma_f32_16x16x32_bf16(au.v, bu[kt].v, acc[mt], 0, 0, 0);
        }
    }

    if (v < NV) {
        uint32_t* yr0 = y0 + ((size_t)b * NV + v) * 32;
        uint32_t* yr1 = y1 + ((size_t)b * NV + v) * 32;
#pragma unroll
        for (int mt = 0; mt < 8; ++mt) {
            const int mo = mt * 16 + lq * 4;
            f32x4 a = acc[mt];
            if (mt < 4) {  // plane 0: + bias, nt store (read exactly once later)
                const float* bp = bias + mo;
                a[0] += bp[0]; a[1] += bp[1]; a[2] += bp[2]; a[3] += bp[3];
                u32x2 p = {bf16pack(a[0], a[1]), bf16pack(a[2], a[3])};
                __builtin_nontemporal_store(p, (u32x2*)(yr0 + (mo >> 1)));
            } else {       // plane 1: hot gather target, keep cached in L2
                u32x2 p = {bf16pack(a[0], a[1]), bf16pack(a[2], a[3])};
                *(u32x2*)(yr1 + ((mo - 64) >> 1)) = p;
            }
        }
    }
}

// ---- K2: gather, 8 lanes/vertex + LDS transpose for coalesced stores ----
// Gather: slot s = lane>>3 owns vertex vloc = wave*8 + s; lane j = lane&7 owns
// 16B chunk j of each 128B y1 row. Store: thread re-maps to (o8 = tid>>5,
// vl = tid&31) and writes 2 o-rows x 32 consecutive v per wave-instruction.
__global__ __launch_bounds__(256) void gather_out(const int* __restrict__ nbr,
                                                  const int* __restrict__ deg,
                                                  const uint32_t* __restrict__ y0,
                                                  const uint32_t* __restrict__ y1,
                                                  float* __restrict__ out) {
    __shared__ float lds[32 * 68];  // [vloc][o], stride 68 to spread banks

    const int b = blockIdx.x & 7;  // same XCD pin as producer
    const int tile = blockIdx.x >> 3;
    const int lane = threadIdx.x & 63;
    const int wave = threadIdx.x >> 6;
    const int s = lane >> 3;
    const int j = lane & 7;
    const int vloc = wave * 8 + s;       // 0..31
    const int v = tile * 32 + vloc;
    const int vc = v < NV ? v : NV - 1;
    const size_t bv = (size_t)b * NV + vc;

    int idxr[ND];
    {
        const int4* p = reinterpret_cast<const int4*>(nbr + bv * ND);
        int4 a0 = p[0], a1 = p[1], a2 = p[2];
        idxr[0] = a0.x; idxr[1] = a0.y; idxr[2]  = a0.z; idxr[3]  = a0.w;
        idxr[4] = a1.x; idxr[5] = a1.y; idxr[6]  = a1.z; idxr[7]  = a1.w;
        idxr[8] = a2.x; idxr[9] = a2.y; idxr[10] = a2.z; idxr[11] = a2.w;
    }
    const int dg = deg[bv];
    const float inv = 1.0f / (float)dg;
    const uint32_t* y1b = y1 + (size_t)b * NV * 32;

    // self row chunk (read once, nt): per instr 8 rows x 128B fully used
    u32x4 su = __builtin_nontemporal_load(
        reinterpret_cast<const u32x4*>(y0 + bv * 32) + j);

    // phase 1: issue all masked row-chunk loads (up to 12 outstanding)
    u32x4 rows[ND];
#pragma unroll
    for (int d = 0; d < ND; ++d) {
        if (d < dg)
            rows[d] = *(reinterpret_cast<const u32x4*>(y1b + (size_t)idxr[d] * 32) + j);
    }

    // phase 2: accumulate
    float ns[8];
#pragma unroll
    for (int t = 0; t < 8; ++t) ns[t] = 0.0f;
#pragma unroll
    for (int d = 0; d < ND; ++d) {
        if (d < dg) {
            u32x4 u = rows[d];
            ns[0] += blo(u[0]); ns[1] += bhi(u[0]);
            ns[2] += blo(u[1]); ns[3] += bhi(u[1]);
            ns[4] += blo(u[2]); ns[5] += bhi(u[2]);
            ns[6] += blo(u[3]); ns[7] += bhi(u[3]);
        }
    }

    // combine + stage to LDS (16B-aligned float4 writes; 68*4 stride)
    {
        float f[8];
        f[0] = __builtin_fmaf(inv, ns[0], blo(su[0]));
        f[1] = __builtin_fmaf(inv, ns[1], bhi(su[0]));
        f[2] = __builtin_fmaf(inv, ns[2], blo(su[1]));
        f[3] = __builtin_fmaf(inv, ns[3], bhi(su[1]));
        f[4] = __builtin_fmaf(inv, ns[4], blo(su[2]));
        f[5] = __builtin_fmaf(inv, ns[5], bhi(su[2]));
        f[6] = __builtin_fmaf(inv, ns[6], blo(su[3]));
        f[7] = __builtin_fmaf(inv, ns[7], bhi(su[3]));
        f32x4 w0 = {f[0], f[1], f[2], f[3]};
        f32x4 w1 = {f[4], f[5], f[6], f[7]};
        *reinterpret_cast<f32x4*>(&lds[vloc * 68 + j * 8])     = w0;
        *reinterpret_cast<f32x4*>(&lds[vloc * 68 + j * 8 + 4]) = w1;
    }
    __syncthreads();

    // store phase: per wave-instruction 2 o-rows x 32 consecutive v (2x128B)
    {
        const int vl = threadIdx.x & 31;
        const int o8 = threadIdx.x >> 5;   // 0..7
        const int vv = tile * 32 + vl;
        if (vv < NV) {
            float* ob = out + (size_t)b * NO * NV + vv;
#pragma unroll
            for (int oo = 0; oo < 8; ++oo) {
                const int o = oo * 8 + o8;
                __builtin_nontemporal_store(lds[vl * 68 + o], ob + (size_t)o * NV);
            }
        }
    }
}

// ---- Fallback (workspace too small): correct but slow ----
__global__ __launch_bounds__(64) void fallback_kernel(const float* __restrict__ x,
                                                      const int* __restrict__ nbr,
                                                      const int* __restrict__ deg,
                                                      const float* __restrict__ W,
                                                      const float* __restrict__ bias,
                                                      float* __restrict__ out) {
    const int bvi = blockIdx.x;
    const int b = bvi / NV, v = bvi % NV;
    const int o = threadIdx.x;
    const int degv = deg[bvi];
    const float inv = 1.0f / (float)degv;
    float acc = bias[o];
    for (int c = 0; c < NC; ++c) {
        const float* xc = x + ((size_t)b * NC + c) * NV;
        float m = 0.0f;
        for (int d = 0; d < degv; ++d) m += xc[nbr[(size_t)bvi * ND + d]];
        acc += W[o * (NC * 2) + c * 2] * xc[v] + W[o * (NC * 2) + c * 2 + 1] * (m * inv);
    }
    out[((size_t)b * NO + o) * NV + v] = acc;
}

extern "C" void kernel_launch(void* const* d_in, const int* in_sizes, int n_in,
                              void* d_out, int out_size, void* d_ws, size_t ws_size,
                              hipStream_t stream) {
    const float* x    = (const float*)d_in[0];
    const int*   nbr  = (const int*)d_in[1];
    const int*   deg  = (const int*)d_in[2];
    const float* W    = (const float*)d_in[3];
    const float* bias = (const float*)d_in[4];
    float* out = (float*)d_out;

    const size_t wcb_dw = 4096;                   // 128x64 bf16 as dwords
    const size_t yplane = (size_t)NB * NV * 32;   // dwords per plane
    const size_t need = (wcb_dw + 2 * yplane) * 4;
    if (ws_size >= need) {
        uint32_t* Wcb = (uint32_t*)d_ws;
        uint32_t* y0 = Wcb + wcb_dw;
        uint32_t* y1 = y0 + yplane;
        wt_kernel<<<dim3(16), 256, 0, stream>>>(W, Wcb);
        ygemm_mfma<<<dim3(NB * GT), 256, 0, stream>>>(x, Wcb, bias, y0, y1);
        gather_out<<<dim3(NB * GVT), 256, 0, stream>>>(nbr, deg, y0, y1, out);
    } else {
        fallback_kernel<<<dim3(NB * NV), 64, 0, stream>>>(x, nbr, deg, W, bias, out);
    }
}

// Round 7
// 164.946 us; speedup vs baseline: 1.2397x; 1.0744x over previous
//
#include <hip/hip_runtime.h>
#include <stdint.h>

// MeshConvPoint: B=8, C=64, V=25000, D=12, O=64
// out[b,o,v] = bias[o] + sum_c W0[o,c]*x[b,c,v] + (1/deg)*sum_{d<deg} y1[b,o,nbr[b,v,d]]
//
// R7: ygemm rebuilt with LDS-staged x tile. R6 counters: ygemm 51.5us at 21%
// HBM / 9% VALU / 2% MFMA = latency-bound on 16 strided scalar dword loads per
// lane (register transpose) + short 16-v waves. Now: 128-v tile staged via
// coalesced 256B loads -> LDS bf16 [v][c] (144B stride, 16B-aligned rows),
// B-frags via single ds_read_b128, 32 v + 32 MFMAs per wave.
// gather_out / wt unchanged (isolation). XCD pin everywhere: blockIdx.x&7 = b.

#define NB 8
#define NC 64
#define NV 25000
#define ND 12
#define NO 64
#define VTILE 128
#define NGT 196        // ceil(25000/128) vertex tiles for gemm
#define GVT 782        // ceil(25000/32)  vertex tiles for gather (32 v / block)

typedef uint32_t u32x4 __attribute__((ext_vector_type(4)));
typedef uint32_t u32x2 __attribute__((ext_vector_type(2)));
typedef __bf16  bf16x8 __attribute__((ext_vector_type(8)));
typedef float   f32x4  __attribute__((ext_vector_type(4)));

__device__ inline uint32_t bf16pack(float a, float b) {
    uint32_t ua = __float_as_uint(a), ub = __float_as_uint(b);
    ua = (ua + 0x7fffu + ((ua >> 16) & 1u)) >> 16;
    ub = (ub + 0x7fffu + ((ub >> 16) & 1u)) >> 16;
    return ua | (ub << 16);
}
__device__ inline float blo(uint32_t u) { return __uint_as_float(u << 16); }
__device__ inline float bhi(uint32_t u) { return __uint_as_float(u & 0xffff0000u); }

// ---- K0: W[o][c][k] -> Wcb[m][c] bf16, m = k*64 + o ----
__global__ __launch_bounds__(256) void wt_kernel(const float* __restrict__ W,
                                                 uint32_t* __restrict__ Wcb) {
    int i = blockIdx.x * 256 + threadIdx.x;  // i in [0, 4096)
    int m = i >> 5;             // 0..127
    int c = (i & 31) * 2;       // 0..62 even
    int k = m >> 6;             // plane
    int o = m & 63;
    float s0 = W[o * (NC * 2) + c * 2 + k];
    float s1 = W[o * (NC * 2) + (c + 1) * 2 + k];
    Wcb[i] = bf16pack(s0, s1);
}

// ---- K1: MFMA GEMM with LDS-staged x tile ----
// xt[v][c] bf16, row stride 72 bf16 = 36 dwords = 144 B (multiple of 16 B so
// ds_read_b128 rows stay aligned; 8-way write conflict accepted: 16 writes/thr).
__global__ __launch_bounds__(256) void ygemm_mfma(const float* __restrict__ x,
                                                  const uint32_t* __restrict__ Wcb,
                                                  const float* __restrict__ bias,
                                                  uint32_t* __restrict__ y0,
                                                  uint32_t* __restrict__ y1) {
    __shared__ uint32_t xt[VTILE * 36];

    const int b = blockIdx.x & 7;      // XCD pin
    const int tile = blockIdx.x >> 3;
    const int vbase = tile * VTILE;
    const int tid = threadIdx.x;
    const float* xb = x + (size_t)b * NC * NV;

    // staging: thread covers v = tid&127, c-pair p = r*2 + (tid>>7), r=0..15
    {
        const int vl = tid & 127;
        const int ph = tid >> 7;       // 0..1
        int vg = vbase + vl;
        if (vg >= NV) vg = NV - 1;
#pragma unroll
        for (int r = 0; r < 16; ++r) {
            const int p = r * 2 + ph;  // 0..31
            const int c = p * 2;
            float s0 = __builtin_nontemporal_load(xb + (size_t)c * NV + vg);
            float s1 = __builtin_nontemporal_load(xb + (size_t)(c + 1) * NV + vg);
            xt[vl * 36 + p] = bf16pack(s0, s1);
        }
    }
    __syncthreads();

    const int lane = tid & 63, wave = tid >> 6;
    const int l15 = lane & 15, lq = lane >> 4;

    // B frags: wave handles subtiles s=0,1 -> vloc = (wave*2+s)*16 + l15.
    // B[k][n]: n = l15 (v), k = lq*8 + j  -> 16 contiguous bytes in xt row.
    union BF { u32x4 q; bf16x8 v; } bf[2][2];  // [sub][kt]
#pragma unroll
    for (int s = 0; s < 2; ++s) {
        const int vloc = (wave * 2 + s) * 16 + l15;
#pragma unroll
        for (int kt = 0; kt < 2; ++kt)
            bf[s][kt].q = *reinterpret_cast<const u32x4*>(&xt[vloc * 36 + kt * 16 + lq * 4]);
    }

    f32x4 acc[2][8];
#pragma unroll
    for (int s = 0; s < 2; ++s)
#pragma unroll
        for (int mt = 0; mt < 8; ++mt) acc[s][mt] = (f32x4){0.f, 0.f, 0.f, 0.f};

    // A frags loaded once per (kt,mt), reused for both subtiles
#pragma unroll
    for (int kt = 0; kt < 2; ++kt) {
#pragma unroll
        for (int mt = 0; mt < 8; ++mt) {
            union { u32x4 q; bf16x8 v; } au;
            au.q = *(const u32x4*)(Wcb + (size_t)(mt * 16 + l15) * 32 + kt * 16 + lq * 4);
#pragma unroll
            for (int s = 0; s < 2; ++s)
                acc[s][mt] = __builtin_amdgcn_mfma_f32_16x16x32_bf16(au.v, bf[s][kt].v,
                                                                     acc[s][mt], 0, 0, 0);
        }
    }

    // D: lane holds D[m = mt*16 + lq*4 + r][n = v], r = 0..3 consecutive o
#pragma unroll
    for (int s = 0; s < 2; ++s) {
        const int v = vbase + (wave * 2 + s) * 16 + l15;
        if (v < NV) {
            uint32_t* yr0 = y0 + ((size_t)b * NV + v) * 32;
            uint32_t* yr1 = y1 + ((size_t)b * NV + v) * 32;
#pragma unroll
            for (int mt = 0; mt < 8; ++mt) {
                const int mo = mt * 16 + lq * 4;
                f32x4 a = acc[s][mt];
                if (mt < 4) {  // plane 0: + bias, nt store (read exactly once later)
                    const float* bp = bias + mo;
                    a[0] += bp[0]; a[1] += bp[1]; a[2] += bp[2]; a[3] += bp[3];
                    u32x2 p = {bf16pack(a[0], a[1]), bf16pack(a[2], a[3])};
                    __builtin_nontemporal_store(p, (u32x2*)(yr0 + (mo >> 1)));
                } else {       // plane 1: hot gather target, keep cached in L2
                    u32x2 p = {bf16pack(a[0], a[1]), bf16pack(a[2], a[3])};
                    *(u32x2*)(yr1 + ((mo - 64) >> 1)) = p;
                }
            }
        }
    }
}

// ---- K2: gather, 8 lanes/vertex + LDS transpose for coalesced stores ----
__global__ __launch_bounds__(256) void gather_out(const int* __restrict__ nbr,
                                                  const int* __restrict__ deg,
                                                  const uint32_t* __restrict__ y0,
                                                  const uint32_t* __restrict__ y1,
                                                  float* __restrict__ out) {
    __shared__ float lds[32 * 68];  // [vloc][o], stride 68 to spread banks

    const int b = blockIdx.x & 7;  // same XCD pin as producer
    const int tile = blockIdx.x >> 3;
    const int lane = threadIdx.x & 63;
    const int wave = threadIdx.x >> 6;
    const int s = lane >> 3;
    const int j = lane & 7;
    const int vloc = wave * 8 + s;       // 0..31
    const int v = tile * 32 + vloc;
    const int vc = v < NV ? v : NV - 1;
    const size_t bv = (size_t)b * NV + vc;

    int idxr[ND];
    {
        const int4* p = reinterpret_cast<const int4*>(nbr + bv * ND);
        int4 a0 = p[0], a1 = p[1], a2 = p[2];
        idxr[0] = a0.x; idxr[1] = a0.y; idxr[2]  = a0.z; idxr[3]  = a0.w;
        idxr[4] = a1.x; idxr[5] = a1.y; idxr[6]  = a1.z; idxr[7]  = a1.w;
        idxr[8] = a2.x; idxr[9] = a2.y; idxr[10] = a2.z; idxr[11] = a2.w;
    }
    const int dg = deg[bv];
    const float inv = 1.0f / (float)dg;
    const uint32_t* y1b = y1 + (size_t)b * NV * 32;

    // self row chunk (read once, nt): per instr 8 rows x 128B fully used
    u32x4 su = __builtin_nontemporal_load(
        reinterpret_cast<const u32x4*>(y0 + bv * 32) + j);

    // phase 1: issue all masked row-chunk loads (up to 12 outstanding)
    u32x4 rows[ND];
#pragma unroll
    for (int d = 0; d < ND; ++d) {
        if (d < dg)
            rows[d] = *(reinterpret_cast<const u32x4*>(y1b + (size_t)idxr[d] * 32) + j);
    }

    // phase 2: accumulate
    float ns[8];
#pragma unroll
    for (int t = 0; t < 8; ++t) ns[t] = 0.0f;
#pragma unroll
    for (int d = 0; d < ND; ++d) {
        if (d < dg) {
            u32x4 u = rows[d];
            ns[0] += blo(u[0]); ns[1] += bhi(u[0]);
            ns[2] += blo(u[1]); ns[3] += bhi(u[1]);
            ns[4] += blo(u[2]); ns[5] += bhi(u[2]);
            ns[6] += blo(u[3]); ns[7] += bhi(u[3]);
        }
    }

    // combine + stage to LDS (16B-aligned float4 writes; 68*4 stride)
    {
        float f[8];
        f[0] = __builtin_fmaf(inv, ns[0], blo(su[0]));
        f[1] = __builtin_fmaf(inv, ns[1], bhi(su[0]));
        f[2] = __builtin_fmaf(inv, ns[2], blo(su[1]));
        f[3] = __builtin_fmaf(inv, ns[3], bhi(su[1]));
        f[4] = __builtin_fmaf(inv, ns[4], blo(su[2]));
        f[5] = __builtin_fmaf(inv, ns[5], bhi(su[2]));
        f[6] = __builtin_fmaf(inv, ns[6], blo(su[3]));
        f[7] = __builtin_fmaf(inv, ns[7], bhi(su[3]));
        f32x4 w0 = {f[0], f[1], f[2], f[3]};
        f32x4 w1 = {f[4], f[5], f[6], f[7]};
        *reinterpret_cast<f32x4*>(&lds[vloc * 68 + j * 8])     = w0;
        *reinterpret_cast<f32x4*>(&lds[vloc * 68 + j * 8 + 4]) = w1;
    }
    __syncthreads();

    // store phase: per wave-instruction 2 o-rows x 32 consecutive v (2x128B)
    {
        const int vl = threadIdx.x & 31;
        const int o8 = threadIdx.x >> 5;   // 0..7
        const int vv = tile * 32 + vl;
        if (vv < NV) {
            float* ob = out + (size_t)b * NO * NV + vv;
#pragma unroll
            for (int oo = 0; oo < 8; ++oo) {
                const int o = oo * 8 + o8;
                __builtin_nontemporal_store(lds[vl * 68 + o], ob + (size_t)o * NV);
            }
        }
    }
}

// ---- Fallback (workspace too small): correct but slow ----
__global__ __launch_bounds__(64) void fallback_kernel(const float* __restrict__ x,
                                                      const int* __restrict__ nbr,
                                                      const int* __restrict__ deg,
                                                      const float* __restrict__ W,
                                                      const float* __restrict__ bias,
                                                      float* __restrict__ out) {
    const int bvi = blockIdx.x;
    const int b = bvi / NV, v = bvi % NV;
    const int o = threadIdx.x;
    const int degv = deg[bvi];
    const float inv = 1.0f / (float)degv;
    float acc = bias[o];
    for (int c = 0; c < NC; ++c) {
        const float* xc = x + ((size_t)b * NC + c) * NV;
        float m = 0.0f;
        for (int d = 0; d < degv; ++d) m += xc[nbr[(size_t)bvi * ND + d]];
        acc += W[o * (NC * 2) + c * 2] * xc[v] + W[o * (NC * 2) + c * 2 + 1] * (m * inv);
    }
    out[((size_t)b * NO + o) * NV + v] = acc;
}

extern "C" void kernel_launch(void* const* d_in, const int* in_sizes, int n_in,
                              void* d_out, int out_size, void* d_ws, size_t ws_size,
                              hipStream_t stream) {
    const float* x    = (const float*)d_in[0];
    const int*   nbr  = (const int*)d_in[1];
    const int*   deg  = (const int*)d_in[2];
    const float* W    = (const float*)d_in[3];
    const float* bias = (const float*)d_in[4];
    float* out = (float*)d_out;

    const size_t wcb_dw = 4096;                   // 128x64 bf16 as dwords
    const size_t yplane = (size_t)NB * NV * 32;   // dwords per plane
    const size_t need = (wcb_dw + 2 * yplane) * 4;
    if (ws_size >= need) {
        uint32_t* Wcb = (uint32_t*)d_ws;
        uint32_t* y0 = Wcb + wcb_dw;
        uint32_t* y1 = y0 + yplane;
        wt_kernel<<<dim3(16), 256, 0, stream>>>(W, Wcb);
        ygemm_mfma<<<dim3(NB * NGT), 256, 0, stream>>>(x, Wcb, bias, y0, y1);
        gather_out<<<dim3(NB * GVT), 256, 0, stream>>>(nbr, deg, y0, y1, out);
    } else {
        fallback_kernel<<<dim3(NB * NV), 64, 0, stream>>>(x, nbr, deg, W, bias, out);
    }
}